// Round 7
// baseline (222.548 us; speedup 1.0000x reference)
//
#include <hip/hip_runtime.h>
#include <hip/hip_bf16.h>

typedef __attribute__((ext_vector_type(8))) short bf16x8;
typedef __attribute__((ext_vector_type(4))) float f32x4;
typedef unsigned short u16;
typedef unsigned int u32;

#define MFMA16(a,b,c) __builtin_amdgcn_mfma_f32_16x16x32_bf16((a),(b),(c),0,0,0)

#if defined(__has_builtin) && __has_builtin(__builtin_amdgcn_exp2f)
#define EXP2(x) __builtin_amdgcn_exp2f(x)
#else
#define EXP2(x) exp2f(x)
#endif

// softmax scale folded into Q at projection time: (1/32) * log2(e)
#define QSCALE 0.045084220027780106f

__device__ __forceinline__ u16 f2bf(float f) {
  union { float f; unsigned int u; } v; v.f = f;
  unsigned int r = v.u + 0x7FFFu + ((v.u >> 16) & 1u);   // RNE
  return (u16)(r >> 16);
}

__device__ __forceinline__ u32 pkbf(float a, float b) {
  union { __hip_bfloat162 h; u32 u; } cv;
  cv.h = __float22bfloat162_rn(make_float2(a, b));
  return cv.u;
}

// async global->LDS, 16B per lane; LDS dest = wave-uniform base + lane*16
__device__ __forceinline__ void gld16(const void* g, void* l) {
  __builtin_amdgcn_global_load_lds(
      (__attribute__((address_space(1))) void*)(g),
      (__attribute__((address_space(3))) void*)(l), 16, 0, 0);
}

// ---------------- cast fp32 -> bf16 (all inputs, one launch) ----------------
__global__ __launch_bounds__(256) void cast_all(
    const float* __restrict__ x, const float* __restrict__ qu,
    const float* __restrict__ wq, const float* __restrict__ wk,
    const float* __restrict__ wv, const float* __restrict__ wo,
    u16* __restrict__ xb, u16* __restrict__ qub,
    u16* __restrict__ wqb, u16* __restrict__ wkb,
    u16* __restrict__ wvb, u16* __restrict__ wob)
{
  int i = blockIdx.x * 256 + threadIdx.x;   // float4 index
  const float4* src; u16* dst; int off;
  if (i < 1048576)      { src = (const float4*)qu; dst = qub; off = i; }
  else if (i < 2097152) { src = (const float4*)x;  dst = xb;  off = i - 1048576; }
  else if (i < 2359296) { src = (const float4*)wq; dst = wqb; off = i - 2097152; }
  else if (i < 2621440) { src = (const float4*)wk; dst = wkb; off = i - 2359296; }
  else if (i < 2883584) { src = (const float4*)wv; dst = wvb; off = i - 2621440; }
  else                  { src = (const float4*)wo; dst = wob; off = i - 2883584; }
  float4 v = src[off];
  ushort4 r; r.x = f2bf(v.x); r.y = f2bf(v.y); r.z = f2bf(v.z); r.w = f2bf(v.w);
  ((ushort4*)dst)[off] = r;
}

// ---------------- fused QKV projection GEMM ----------------
// z=0: Q*(scale*log2e) -> [B,H,N,D]; z=1: K -> [B,H,N,D]  (C^T orientation,
// packed 8-B stores). z=2: V -> [B,H,D,N'] token-permuted
// (k' = (t&32)|((t&12)<<1)|((t&16)>>2)|(t&3)), packed 8-B stores.
__global__ __launch_bounds__(256) void gemm_qkv(
    const u16* __restrict__ qub, const u16* __restrict__ xb,
    const u16* __restrict__ wqb, const u16* __restrict__ wkb, const u16* __restrict__ wvb,
    const float* __restrict__ bq, const float* __restrict__ bk, const float* __restrict__ bv,
    u16* __restrict__ qhd, u16* __restrict__ khd, u16* __restrict__ vtd)
{
  __shared__ u16 As[128 * 64];
  __shared__ u16 Bs[128 * 64];
  int tid = threadIdx.x, w = tid >> 6, lane = tid & 63;
  int c = lane & 15, quad = lane >> 4;
  int bm = blockIdx.x, bn = blockIdx.y, z = blockIdx.z;
  int wm = w >> 1, wn = w & 1;
  const u16* A = (z == 0) ? qub : xb;
  const u16* W = (z == 0) ? wqb : (z == 1) ? wkb : wvb;
  f32x4 acc[4][4] = {};
  for (int k0 = 0; k0 < 1024; k0 += 64) {
#pragma unroll
    for (int i = 0; i < 4; i++) {
      int seg = i * 256 + w * 64 + lane;          // physical 8-elem segment
      int row = seg >> 3, pseg = seg & 7;
      int lseg = pseg ^ (row & 7);                // logical k-segment (XOR swizzle)
      gld16(A + (size_t)(bm * 128 + row) * 1024 + k0 + lseg * 8,
            &As[(i * 256 + w * 64) * 8]);
      gld16(W + (size_t)(bn * 128 + row) * 1024 + k0 + lseg * 8,
            &Bs[(i * 256 + w * 64) * 8]);
    }
    __syncthreads();
#pragma unroll
    for (int ks = 0; ks < 2; ks++) {
      bf16x8 af[4], bfr[4];
#pragma unroll
      for (int mt = 0; mt < 4; mt++) {
        int row = wm * 64 + mt * 16 + c;
        int cseg = (ks * 4 + quad) ^ (row & 7);
        af[mt] = *(const bf16x8*)&As[(row * 8 + cseg) * 8];
      }
#pragma unroll
      for (int nt = 0; nt < 4; nt++) {
        int row = wn * 64 + nt * 16 + c;
        int cseg = (ks * 4 + quad) ^ (row & 7);
        bfr[nt] = *(const bf16x8*)&Bs[(row * 8 + cseg) * 8];
      }
      if (z < 2) {
        // C^T: rows = channels (W frags as A-operand), cols = tokens
#pragma unroll
        for (int ct = 0; ct < 4; ct++)
#pragma unroll
          for (int tt = 0; tt < 4; tt++)
            acc[ct][tt] = MFMA16(bfr[ct], af[tt], acc[ct][tt]);
      } else {
#pragma unroll
        for (int mt = 0; mt < 4; mt++)
#pragma unroll
          for (int nt = 0; nt < 4; nt++)
            acc[mt][nt] = MFMA16(af[mt], bfr[nt], acc[mt][nt]);
      }
    }
    __syncthreads();
  }
  if (z < 2) {
    const float* bias = (z == 0) ? bq : bk;
    u16* dst = (z == 0) ? qhd : khd;
    float sc = (z == 0) ? QSCALE : 1.0f;
    float4 bbs[4];
#pragma unroll
    for (int ct = 0; ct < 4; ct++) {
      float4 b4 = *(const float4*)&bias[bn * 128 + wn * 64 + ct * 16 + quad * 4];
      bbs[ct].x = b4.x * sc; bbs[ct].y = b4.y * sc;
      bbs[ct].z = b4.z * sc; bbs[ct].w = b4.w * sc;
    }
#pragma unroll
    for (int ct = 0; ct < 4; ct++) {
      int ch = bn * 128 + wn * 64 + ct * 16 + quad * 4;
      int h = ch >> 6, d0 = ch & 63;
#pragma unroll
      for (int tt = 0; tt < 4; tt++) {
        int tok = bm * 128 + wm * 64 + tt * 16 + c;
        int b = tok >> 11, n = tok & 2047;
        float v0 = fmaf(acc[ct][tt][0], sc, bbs[ct].x);
        float v1 = fmaf(acc[ct][tt][1], sc, bbs[ct].y);
        float v2 = fmaf(acc[ct][tt][2], sc, bbs[ct].z);
        float v3 = fmaf(acc[ct][tt][3], sc, bbs[ct].w);
        uint2 pk; pk.x = pkbf(v0, v1); pk.y = pkbf(v2, v3);
        *(uint2*)&dst[((size_t)(b * 16 + h) * 2048 + n) * 64 + d0] = pk;
      }
    }
  } else {
    float bval[4];
#pragma unroll
    for (int nt = 0; nt < 4; nt++)
      bval[nt] = bv[bn * 128 + wn * 64 + nt * 16 + c];
#pragma unroll
    for (int mt = 0; mt < 4; mt++) {
      int tokl = (mt & 2) * 16 + quad * 8 + (mt & 1) * 4;   // permuted, +j
      int tok = bm * 128 + wm * 64 + tokl;
      int b = tok >> 11, np = tok & 2047;
#pragma unroll
      for (int nt = 0; nt < 4; nt++) {
        int ch = bn * 128 + wn * 64 + nt * 16 + c;
        int h = ch >> 6, d = ch & 63;
        float v0 = acc[mt][nt][0] + bval[nt];
        float v1 = acc[mt][nt][1] + bval[nt];
        float v2 = acc[mt][nt][2] + bval[nt];
        float v3 = acc[mt][nt][3] + bval[nt];
        uint2 pk; pk.x = pkbf(v0, v1); pk.y = pkbf(v2, v3);
        *(uint2*)&vtd[((size_t)(b * 16 + h) * 64 + d) * 2048 + np] = pk;
      }
    }
  }
}

// ---------------- attention v7: KV-split x2, 32-key tiles, 8 blocks/CU ------
// grid (32 bh, 32 qt, 2 kv) = 2048 blocks of 128 thr; wave owns 32 q x 1024 k.
// Writes unnormalized fp32 O-partials + row-sums; combine kernel merges.
// XCD = bh%8 (linear%8) -> K/V L2 locality preserved.
__global__ __launch_bounds__(128) void attn(
    const u16* __restrict__ qh, const u16* __restrict__ kh,
    const u16* __restrict__ vt,
    float* __restrict__ po0, float* __restrict__ po1, float* __restrict__ pl)
{
  __shared__ u16 Kbuf[2][32 * 64];   // 4 KB each
  __shared__ u16 Vbuf[2][64 * 32];   // 4 KB each
  int tid = threadIdx.x, w = tid >> 6, lane = tid & 63;
  int c = lane & 15, quad = lane >> 4;
  int bh = blockIdx.x, qt = blockIdx.y, kv = blockIdx.z;
  const u16* qp = qh + ((size_t)bh * 2048 + qt * 64 + w * 32) * 64;

  // Q B-frags: B[k=d][n=q], lane c = q-col
  bf16x8 Qf[2][2];
#pragma unroll
  for (int qt2 = 0; qt2 < 2; qt2++)
#pragma unroll
    for (int ks = 0; ks < 2; ks++)
      Qf[qt2][ks] = *(const bf16x8*)(qp + (size_t)(qt2 * 16 + c) * 64 + ks * 32 + quad * 8);

  // lane-invariant LDS fragment offsets (elements)
  int offK0 = c * 64 + ((quad) ^ (c & 7)) * 8;
  int offK1 = c * 64 + ((4 + quad) ^ (c & 7)) * 8;
  int offV  = c * 32 + ((quad ^ ((c >> 1) & 3))) * 8;

  // staging pointers (strength-reduced)
  int kr = w * 16 + (lane >> 3);                       // K rows: kr, kr+8
  const u16* kg = kh + (size_t)bh * 2048 * 64 + kv * 1024 * 64 +
                  kr * 64 + ((lane & 7) ^ (kr & 7)) * 8;
  int vr = w * 32 + (lane >> 2);                       // V d-rows: vr, vr+16
  const u16* vg = vt + (size_t)bh * 64 * 2048 + vr * 2048 + kv * 1024 +
                  ((lane & 3) ^ ((vr >> 1) & 3)) * 8;
  // wave-uniform LDS dests
  u16* kd0[2] = {&Kbuf[0][(w * 2) * 512],     &Kbuf[1][(w * 2) * 512]};
  u16* kd1[2] = {&Kbuf[0][(w * 2 + 1) * 512], &Kbuf[1][(w * 2 + 1) * 512]};
  u16* vd0[2] = {&Vbuf[0][(w * 2) * 512],     &Vbuf[1][(w * 2) * 512]};
  u16* vd1[2] = {&Vbuf[0][(w * 2 + 1) * 512], &Vbuf[1][(w * 2 + 1) * 512]};

#define STAGE(B)                                                                \
  {                                                                             \
    gld16(kg,         kd0[B]); gld16(kg + 512,       kd1[B]);                   \
    gld16(vg,         vd0[B]); gld16(vg + 16 * 2048, vd1[B]);                   \
    kg += 2048; vg += 32;                                                       \
  }

  STAGE(0)
  __syncthreads();

  f32x4 O[2][4] = {};
  f32x4 Lacc[2] = {};
  const f32x4 Zv = {};
  bf16x8 vone;
#pragma unroll
  for (int j = 0; j < 8; j++) vone[j] = (short)0x3F80;   // bf16 1.0

#define ITER(PH, PREF)                                                          \
  {                                                                             \
    if (PREF) STAGE(PH ^ 1)                                                     \
    const u16* Ks = Kbuf[PH];                                                   \
    const u16* Vs = Vbuf[PH];                                                   \
    bf16x8 Kf[2][2];                                                            \
    _Pragma("unroll") for (int nt = 0; nt < 2; nt++) {                          \
      Kf[nt][0] = *(const bf16x8*)&Ks[offK0 + nt * 1024];                       \
      Kf[nt][1] = *(const bf16x8*)&Ks[offK1 + nt * 1024];                       \
    }                                                                           \
    f32x4 S[2][2];                                                              \
    _Pragma("unroll") for (int qt2 = 0; qt2 < 2; qt2++)                         \
      _Pragma("unroll") for (int nt = 0; nt < 2; nt++) {                        \
        S[qt2][nt] = MFMA16(Kf[nt][0], Qf[qt2][0], Zv);                         \
        S[qt2][nt] = MFMA16(Kf[nt][1], Qf[qt2][1], S[qt2][nt]);                 \
      }                                                                         \
    bf16x8 pa[2];                                                               \
    _Pragma("unroll") for (int qt2 = 0; qt2 < 2; qt2++) {                       \
      float e0 = EXP2(S[qt2][0][0]), e1 = EXP2(S[qt2][0][1]);                   \
      float e2 = EXP2(S[qt2][0][2]), e3 = EXP2(S[qt2][0][3]);                   \
      float e4 = EXP2(S[qt2][1][0]), e5 = EXP2(S[qt2][1][1]);                   \
      float e6 = EXP2(S[qt2][1][2]), e7 = EXP2(S[qt2][1][3]);                   \
      union { uint4 u; bf16x8 v; } cv;                                          \
      cv.u.x = pkbf(e0, e1); cv.u.y = pkbf(e2, e3);                             \
      cv.u.z = pkbf(e4, e5); cv.u.w = pkbf(e6, e7);                             \
      pa[qt2] = cv.v;                                                           \
    }                                                                           \
    Lacc[0] = MFMA16(pa[0], vone, Lacc[0]);                                     \
    Lacc[1] = MFMA16(pa[1], vone, Lacc[1]);                                     \
    bf16x8 Vf[4];                                                               \
    _Pragma("unroll") for (int dt = 0; dt < 4; dt++)                            \
      Vf[dt] = *(const bf16x8*)&Vs[offV + dt * 512];                            \
    _Pragma("unroll") for (int qt2 = 0; qt2 < 2; qt2++)                         \
      _Pragma("unroll") for (int dt = 0; dt < 4; dt++)                          \
        O[qt2][dt] = MFMA16(pa[qt2], Vf[dt], O[qt2][dt]);                       \
    __syncthreads();                                                            \
  }

  for (int kt2 = 0; kt2 < 15; kt2++) {
    ITER(0, 1)
    ITER(1, 1)
  }
  ITER(0, 1)
  ITER(1, 0)
#undef ITER
#undef STAGE

  // epilogue: write fp32 partials (unnormalized) + row-sums
  float* pob = (kv ? po1 : po0) +
               (((size_t)bh * 2048) + qt * 64 + w * 32) * 64;
  float* plb = pl + (size_t)kv * 65536 + bh * 2048 + qt * 64 + w * 32;
#pragma unroll
  for (int qt2 = 0; qt2 < 2; qt2++)
#pragma unroll
    for (int j = 0; j < 4; j++) {
      int nl = qt2 * 16 + quad * 4 + j;
#pragma unroll
      for (int dt = 0; dt < 4; dt++)
        pob[nl * 64 + dt * 16 + c] = O[qt2][dt][j];
      if (c == 0) plb[nl] = Lacc[qt2][j];
    }
}

// ---------------- combine: merge KV halves, normalize, emit bf16 ----------
__global__ __launch_bounds__(256) void combine(
    const float* __restrict__ po0, const float* __restrict__ po1,
    const float* __restrict__ pl, u16* __restrict__ ot)
{
  int t = blockIdx.x * 256 + threadIdx.x;   // 1,048,576 threads
  int dq = t & 15, n = (t >> 4) & 2047, bh = t >> 15;
  size_t i0 = (((size_t)bh * 2048) + n) * 64 + dq * 4;
  f32x4 a = *(const f32x4*)(po0 + i0);
  f32x4 b = *(const f32x4*)(po1 + i0);
  float l = pl[bh * 2048 + n] + pl[65536 + bh * 2048 + n];
  float inv = 1.0f / l;
  int b_ = bh >> 4, h = bh & 15;
  uint2 pk;
  pk.x = pkbf((a[0] + b[0]) * inv, (a[1] + b[1]) * inv);
  pk.y = pkbf((a[2] + b[2]) * inv, (a[3] + b[3]) * inv);
  *(uint2*)(ot + (((size_t)b_ * 2048 + n) * 16 + h) * 64 + dq * 4) = pk;
}

// ---------------- output projection GEMM (fp32 out), 64x128 tile ----------
__global__ __launch_bounds__(256) void gemm_out(
    const u16* __restrict__ Aot, const u16* __restrict__ wob,
    const float* __restrict__ bo, float* __restrict__ out)
{
  __shared__ u16 As[64 * 64];
  __shared__ u16 Bs[128 * 64];
  int tid = threadIdx.x, w = tid >> 6, lane = tid & 63;
  int bm = blockIdx.x, bn = blockIdx.y;
  int wm = w >> 1, wn = w & 1;
  f32x4 acc[2][4] = {};
  for (int k0 = 0; k0 < 1024; k0 += 64) {
#pragma unroll
    for (int i = 0; i < 2; i++) {
      int seg = i * 256 + tid;
      int row = seg >> 3, pseg = seg & 7;
      int lseg = pseg ^ (row & 7);
      gld16(Aot + (size_t)(bm * 64 + row) * 1024 + k0 + lseg * 8,
            &As[(i * 256 + tid - (tid & 7)) * 8 + (tid & 7) * 8]);
    }
#pragma unroll
    for (int i = 0; i < 4; i++) {
      int seg = i * 256 + tid;
      int row = seg >> 3, pseg = seg & 7;
      int lseg = pseg ^ (row & 7);
      gld16(wob + (size_t)(bn * 128 + row) * 1024 + k0 + lseg * 8,
            &Bs[(i * 256 + tid - (tid & 7)) * 8 + (tid & 7) * 8]);
    }
    __syncthreads();
#pragma unroll
    for (int ks = 0; ks < 2; ks++) {
      bf16x8 af[2], bfr[4];
#pragma unroll
      for (int mt = 0; mt < 2; mt++) {
        int row = wm * 32 + mt * 16 + (lane & 15);
        int cseg = (ks * 4 + (lane >> 4)) ^ (row & 7);
        af[mt] = *(const bf16x8*)&As[(row * 8 + cseg) * 8];
      }
#pragma unroll
      for (int nt = 0; nt < 4; nt++) {
        int row = wn * 64 + nt * 16 + (lane & 15);
        int cseg = (ks * 4 + (lane >> 4)) ^ (row & 7);
        bfr[nt] = *(const bf16x8*)&Bs[(row * 8 + cseg) * 8];
      }
#pragma unroll
      for (int mt = 0; mt < 2; mt++)
#pragma unroll
        for (int nt = 0; nt < 4; nt++)
          acc[mt][nt] = MFMA16(af[mt], bfr[nt], acc[mt][nt]);
    }
    __syncthreads();
  }
#pragma unroll
  for (int nt = 0; nt < 4; nt++) {
    int o = bn * 128 + wn * 64 + nt * 16 + (lane & 15);
    float bval = bo[o];
#pragma unroll
    for (int mt = 0; mt < 2; mt++)
#pragma unroll
      for (int j = 0; j < 4; j++) {
        int m = bm * 64 + wm * 32 + mt * 16 + (lane >> 4) * 4 + j;
        out[(size_t)m * 1024 + o] = acc[mt][nt][j] + bval;
      }
  }
}

extern "C" void kernel_launch(void* const* d_in, const int* in_sizes, int n_in,
                              void* d_out, int out_size, void* d_ws, size_t ws_size,
                              hipStream_t stream)
{
  const float* x  = (const float*)d_in[0];
  const float* qu = (const float*)d_in[1];
  const float* wq = (const float*)d_in[2];
  const float* bq = (const float*)d_in[3];
  const float* wk = (const float*)d_in[4];
  const float* bk = (const float*)d_in[5];
  const float* wv = (const float*)d_in[6];
  const float* bv = (const float*)d_in[7];
  const float* wo = (const float*)d_in[8];
  const float* bo = (const float*)d_in[9];
  float* out = (float*)d_out;
  char* ws = (char*)d_ws;
  // layout: xb/qub (0-16MB) are reused as PO0 after gemm_qkv consumes them.
  u16* xb  = (u16*)(ws + (size_t)0);          // 8 MB   (dead after gemm_qkv)
  u16* qub = (u16*)(ws + ((size_t)8  << 20)); // 8 MB   (dead after gemm_qkv)
  u16* wqb = (u16*)(ws + ((size_t)16 << 20)); // 2 MB
  u16* wkb = (u16*)(ws + ((size_t)18 << 20)); // 2 MB
  u16* wvb = (u16*)(ws + ((size_t)20 << 20)); // 2 MB
  u16* wob = (u16*)(ws + ((size_t)22 << 20)); // 2 MB
  u16* qhd = (u16*)(ws + ((size_t)24 << 20)); // 8 MB  Q-scaled [B,H,N,D]
  u16* khd = (u16*)(ws + ((size_t)32 << 20)); // 8 MB  K [B,H,N,D]
  u16* vtd = (u16*)(ws + ((size_t)40 << 20)); // 8 MB  V^T permuted [B,H,D,N']
  u16* otd = (u16*)(ws + ((size_t)48 << 20)); // 8 MB  attn out [B,N,H,D]
  float* po0 = (float*)(ws + (size_t)0);          // 16 MB fp32 partial (kv=0)
  float* po1 = (float*)(ws + ((size_t)56 << 20)); // 16 MB fp32 partial (kv=1)
  float* pl  = (float*)(ws + ((size_t)72 << 20)); // 512 KB row-sums [2][B*H*N]

  cast_all<<<12288, 256, 0, stream>>>(x, qu, wq, wk, wv, wo,
                                      xb, qub, wqb, wkb, wvb, wob);
  gemm_qkv<<<dim3(32, 8, 3), 256, 0, stream>>>(qub, xb, wqb, wkb, wvb,
                                               bq, bk, bv, qhd, khd, vtd);
  attn<<<dim3(32, 32, 2), 128, 0, stream>>>(qhd, khd, vtd, po0, po1, pl);
  combine<<<4096, 256, 0, stream>>>(po0, po1, pl, otd);
  gemm_out<<<dim3(64, 8), 256, 0, stream>>>(otd, wob, bo, out);
}

// Round 8
// 209.477 us; speedup vs baseline: 1.0624x; 1.0624x over previous
//
#include <hip/hip_runtime.h>
#include <hip/hip_bf16.h>

typedef __attribute__((ext_vector_type(8))) short bf16x8;
typedef __attribute__((ext_vector_type(4))) float f32x4;
typedef unsigned short u16;
typedef unsigned int u32;

#define MFMA16(a,b,c) __builtin_amdgcn_mfma_f32_16x16x32_bf16((a),(b),(c),0,0,0)

#if defined(__has_builtin) && __has_builtin(__builtin_amdgcn_exp2f)
#define EXP2(x) __builtin_amdgcn_exp2f(x)
#else
#define EXP2(x) exp2f(x)
#endif

// softmax scale folded into Q at projection time: (1/32) * log2(e)
#define QSCALE 0.045084220027780106f

__device__ __forceinline__ u16 f2bf(float f) {
  union { float f; unsigned int u; } v; v.f = f;
  unsigned int r = v.u + 0x7FFFu + ((v.u >> 16) & 1u);   // RNE
  return (u16)(r >> 16);
}

__device__ __forceinline__ u32 pkbf(float a, float b) {
  union { __hip_bfloat162 h; u32 u; } cv;
  cv.h = __float22bfloat162_rn(make_float2(a, b));
  return cv.u;
}

// async global->LDS, 16B per lane; LDS dest = wave-uniform base + lane*16
__device__ __forceinline__ void gld16(const void* g, void* l) {
  __builtin_amdgcn_global_load_lds(
      (__attribute__((address_space(1))) void*)(g),
      (__attribute__((address_space(3))) void*)(l), 16, 0, 0);
}

// ---------------- cast fp32 -> bf16 (all inputs, one launch) ----------------
__global__ __launch_bounds__(256) void cast_all(
    const float* __restrict__ x, const float* __restrict__ qu,
    const float* __restrict__ wq, const float* __restrict__ wk,
    const float* __restrict__ wv, const float* __restrict__ wo,
    u16* __restrict__ xb, u16* __restrict__ qub,
    u16* __restrict__ wqb, u16* __restrict__ wkb,
    u16* __restrict__ wvb, u16* __restrict__ wob)
{
  int i = blockIdx.x * 256 + threadIdx.x;   // float4 index
  const float4* src; u16* dst; int off;
  if (i < 1048576)      { src = (const float4*)qu; dst = qub; off = i; }
  else if (i < 2097152) { src = (const float4*)x;  dst = xb;  off = i - 1048576; }
  else if (i < 2359296) { src = (const float4*)wq; dst = wqb; off = i - 2097152; }
  else if (i < 2621440) { src = (const float4*)wk; dst = wkb; off = i - 2359296; }
  else if (i < 2883584) { src = (const float4*)wv; dst = wvb; off = i - 2621440; }
  else                  { src = (const float4*)wo; dst = wob; off = i - 2883584; }
  float4 v = src[off];
  ushort4 r; r.x = f2bf(v.x); r.y = f2bf(v.y); r.z = f2bf(v.z); r.w = f2bf(v.w);
  ((ushort4*)dst)[off] = r;
}

// ---------------- fused QKV projection GEMM, 64x128 tile, 6 blocks/CU -------
// z=0: Q*(scale*log2e) -> [B,H,N,D]; z=1: K -> [B,H,N,D]  (C^T orientation,
// packed 8-B stores). z=2: V -> [B,H,D,N'] token-permuted
// (k' = (t&32)|((t&12)<<1)|((t&16)>>2)|(t&3)), packed 8-B stores.
// 4 waves 2x2; wave = 32M x 64N.
__global__ __launch_bounds__(256) void gemm_qkv(
    const u16* __restrict__ qub, const u16* __restrict__ xb,
    const u16* __restrict__ wqb, const u16* __restrict__ wkb, const u16* __restrict__ wvb,
    const float* __restrict__ bq, const float* __restrict__ bk, const float* __restrict__ bv,
    u16* __restrict__ qhd, u16* __restrict__ khd, u16* __restrict__ vtd)
{
  __shared__ u16 As[64 * 64];    // 8 KB
  __shared__ u16 Bs[128 * 64];   // 16 KB
  int tid = threadIdx.x, w = tid >> 6, lane = tid & 63;
  int c = lane & 15, quad = lane >> 4;
  int bm = blockIdx.x, bn = blockIdx.y, z = blockIdx.z;
  int wm = w >> 1, wn = w & 1;
  const u16* A = (z == 0) ? qub : xb;
  const u16* W = (z == 0) ? wqb : (z == 1) ? wkb : wvb;
  f32x4 acc[8] = {};
  for (int k0 = 0; k0 < 1024; k0 += 64) {
#pragma unroll
    for (int i = 0; i < 2; i++) {
      int seg = i * 256 + tid;
      int row = seg >> 3, pseg = seg & 7;
      int lseg = pseg ^ (row & 7);
      gld16(A + (size_t)(bm * 64 + row) * 1024 + k0 + lseg * 8, &As[seg * 8]);
    }
#pragma unroll
    for (int i = 0; i < 4; i++) {
      int seg = i * 256 + tid;
      int row = seg >> 3, pseg = seg & 7;
      int lseg = pseg ^ (row & 7);
      gld16(W + (size_t)(bn * 128 + row) * 1024 + k0 + lseg * 8, &Bs[seg * 8]);
    }
    __syncthreads();
#pragma unroll
    for (int ks = 0; ks < 2; ks++) {
      bf16x8 af[2], bfr[4];
#pragma unroll
      for (int mt = 0; mt < 2; mt++) {
        int row = wm * 32 + mt * 16 + c;
        int cseg = (ks * 4 + quad) ^ (row & 7);
        af[mt] = *(const bf16x8*)&As[(row * 8 + cseg) * 8];
      }
#pragma unroll
      for (int nt = 0; nt < 4; nt++) {
        int row = wn * 64 + nt * 16 + c;
        int cseg = (ks * 4 + quad) ^ (row & 7);
        bfr[nt] = *(const bf16x8*)&Bs[(row * 8 + cseg) * 8];
      }
      if (z < 2) {
        // C^T: rows = channels (W frags as A-operand), cols = tokens
#pragma unroll
        for (int ct = 0; ct < 4; ct++)
#pragma unroll
          for (int tt = 0; tt < 2; tt++)
            acc[ct * 2 + tt] = MFMA16(bfr[ct], af[tt], acc[ct * 2 + tt]);
      } else {
#pragma unroll
        for (int mt = 0; mt < 2; mt++)
#pragma unroll
          for (int nt = 0; nt < 4; nt++)
            acc[mt * 4 + nt] = MFMA16(af[mt], bfr[nt], acc[mt * 4 + nt]);
      }
    }
    __syncthreads();
  }
  if (z < 2) {
    const float* bias = (z == 0) ? bq : bk;
    u16* dst = (z == 0) ? qhd : khd;
    float sc = (z == 0) ? QSCALE : 1.0f;
    float4 bbs[4];
#pragma unroll
    for (int ct = 0; ct < 4; ct++) {
      float4 b4 = *(const float4*)&bias[bn * 128 + wn * 64 + ct * 16 + quad * 4];
      bbs[ct].x = b4.x * sc; bbs[ct].y = b4.y * sc;
      bbs[ct].z = b4.z * sc; bbs[ct].w = b4.w * sc;
    }
#pragma unroll
    for (int ct = 0; ct < 4; ct++) {
      int ch = bn * 128 + wn * 64 + ct * 16 + quad * 4;
      int h = ch >> 6, d0 = ch & 63;
#pragma unroll
      for (int tt = 0; tt < 2; tt++) {
        int tok = bm * 64 + wm * 32 + tt * 16 + c;
        int b = tok >> 11, n = tok & 2047;
        float v0 = fmaf(acc[ct * 2 + tt][0], sc, bbs[ct].x);
        float v1 = fmaf(acc[ct * 2 + tt][1], sc, bbs[ct].y);
        float v2 = fmaf(acc[ct * 2 + tt][2], sc, bbs[ct].z);
        float v3 = fmaf(acc[ct * 2 + tt][3], sc, bbs[ct].w);
        uint2 pk; pk.x = pkbf(v0, v1); pk.y = pkbf(v2, v3);
        *(uint2*)&dst[((size_t)(b * 16 + h) * 2048 + n) * 64 + d0] = pk;
      }
    }
  } else {
    float bval[4];
#pragma unroll
    for (int nt = 0; nt < 4; nt++)
      bval[nt] = bv[bn * 128 + wn * 64 + nt * 16 + c];
#pragma unroll
    for (int mt = 0; mt < 2; mt++) {
      int l0 = wm * 32 + mt * 16 + quad * 4;                 // token-local 0..63
      int l0p = (l0 & 32) | ((l0 & 12) << 1) | ((l0 & 16) >> 2);  // permuted
      int tok = bm * 64 + l0p;
      int b = tok >> 11, np = tok & 2047;
#pragma unroll
      for (int nt = 0; nt < 4; nt++) {
        int ch = bn * 128 + wn * 64 + nt * 16 + c;
        int h = ch >> 6, d = ch & 63;
        float v0 = acc[mt * 4 + nt][0] + bval[nt];
        float v1 = acc[mt * 4 + nt][1] + bval[nt];
        float v2 = acc[mt * 4 + nt][2] + bval[nt];
        float v3 = acc[mt * 4 + nt][3] + bval[nt];
        uint2 pk; pk.x = pkbf(v0, v1); pk.y = pkbf(v2, v3);
        *(uint2*)&vtd[((size_t)(b * 16 + h) * 64 + d) * 2048 + np] = pk;
      }
    }
  }
}

// ---------------- attention v6 (reverted): 4 blocks/CU, 64-key tiles --------
// grid (32 bh, 32 qt): 1024 blocks of 128 threads (2 waves), 64-q tile,
// wave owns 32 q. Same-bh blocks land on one XCD (linear%8 heuristic).
// S^T + in-register P + dbuf LDS K/V, 1 barrier/iter.
__global__ __launch_bounds__(128) void attn(
    const u16* __restrict__ qh, const u16* __restrict__ kh,
    const u16* __restrict__ vt, u16* __restrict__ ot)
{
  __shared__ u16 Kbuf[2][64 * 64];   // 8 KB each buf
  __shared__ u16 Vbuf[2][64 * 64];
  int tid = threadIdx.x, w = tid >> 6, lane = tid & 63;
  int c = lane & 15, quad = lane >> 4;
  int bh = blockIdx.x, qt = blockIdx.y;
  const u16* qp = qh + ((size_t)bh * 2048 + qt * 64 + w * 32) * 64;

  // Q B-frags in registers: B[k=d][n=q], lane c = q-col
  bf16x8 Qf[2][2];
#pragma unroll
  for (int qt2 = 0; qt2 < 2; qt2++)
#pragma unroll
    for (int ks = 0; ks < 2; ks++)
      Qf[qt2][ks] = *(const bf16x8*)(qp + (size_t)(qt2 * 16 + c) * 64 + ks * 32 + quad * 8);

  // hoisted lane-invariant LDS fragment offsets (elements)
  int off0 = c * 64 + ((quad) ^ (c & 7)) * 8;
  int off1 = c * 64 + ((4 + quad) ^ (c & 7)) * 8;

  // staging: wave w covers rows {c2*16 + w*8 + (lane>>3)}, c2 = 0..3
  int sr = lane >> 3;                 // 0..7
  int row0 = w * 8 + sr;              // 0..15 ; row0&7 == sr&7
  int sls = (lane & 7) ^ (sr & 7);    // XOR swizzle
  const u16* kg = kh + (size_t)bh * 2048 * 64 + row0 * 64 + sls * 8;
  const u16* vg = vt + (size_t)bh * 64 * 2048 + row0 * 2048 + sls * 8;

#define STAGE(B)                                                                \
  {                                                                             \
    gld16(kg,          &Kbuf[B][(w * 64) * 8]);                                 \
    gld16(kg + 1024,   &Kbuf[B][(128 + w * 64) * 8]);                           \
    gld16(kg + 2048,   &Kbuf[B][(256 + w * 64) * 8]);                           \
    gld16(kg + 3072,   &Kbuf[B][(384 + w * 64) * 8]);                           \
    gld16(vg,          &Vbuf[B][(w * 64) * 8]);                                 \
    gld16(vg + 32768,  &Vbuf[B][(128 + w * 64) * 8]);                           \
    gld16(vg + 65536,  &Vbuf[B][(256 + w * 64) * 8]);                           \
    gld16(vg + 98304,  &Vbuf[B][(384 + w * 64) * 8]);                           \
    kg += 4096; vg += 64;                                                       \
  }

  STAGE(0)
  __syncthreads();

  f32x4 O[2][4] = {};
  f32x4 Lacc[2] = {};
  bf16x8 vone;
#pragma unroll
  for (int j = 0; j < 8; j++) vone[j] = (short)0x3F80;   // bf16 1.0

#define ITER(PH, PREF)                                                          \
  {                                                                             \
    if (PREF) STAGE(PH ^ 1)                                                     \
    const u16* Ks = Kbuf[PH];                                                   \
    const u16* Vs = Vbuf[PH];                                                   \
    bf16x8 Kf[4][2];                                                            \
    _Pragma("unroll") for (int nt = 0; nt < 4; nt++) {                          \
      Kf[nt][0] = *(const bf16x8*)&Ks[off0 + nt * 1024];                        \
      Kf[nt][1] = *(const bf16x8*)&Ks[off1 + nt * 1024];                        \
    }                                                                           \
    f32x4 S[2][4] = {};                                                         \
    _Pragma("unroll") for (int qt2 = 0; qt2 < 2; qt2++)                         \
      _Pragma("unroll") for (int nt = 0; nt < 4; nt++) {                        \
        S[qt2][nt] = MFMA16(Kf[nt][0], Qf[qt2][0], S[qt2][nt]);                 \
        S[qt2][nt] = MFMA16(Kf[nt][1], Qf[qt2][1], S[qt2][nt]);                 \
      }                                                                         \
    bf16x8 pa[2][2];                                                            \
    _Pragma("unroll") for (int qt2 = 0; qt2 < 2; qt2++)                         \
      _Pragma("unroll") for (int i = 0; i < 2; i++) {                           \
        float e0 = EXP2(S[qt2][2 * i][0]), e1 = EXP2(S[qt2][2 * i][1]);         \
        float e2 = EXP2(S[qt2][2 * i][2]), e3 = EXP2(S[qt2][2 * i][3]);         \
        float e4 = EXP2(S[qt2][2 * i + 1][0]), e5 = EXP2(S[qt2][2 * i + 1][1]); \
        float e6 = EXP2(S[qt2][2 * i + 1][2]), e7 = EXP2(S[qt2][2 * i + 1][3]); \
        union { uint4 u; bf16x8 v; } cv;                                        \
        cv.u.x = pkbf(e0, e1); cv.u.y = pkbf(e2, e3);                           \
        cv.u.z = pkbf(e4, e5); cv.u.w = pkbf(e6, e7);                           \
        pa[qt2][i] = cv.v;                                                      \
      }                                                                         \
    Lacc[0] = MFMA16(pa[0][0], vone, Lacc[0]);                                  \
    Lacc[0] = MFMA16(pa[0][1], vone, Lacc[0]);                                  \
    Lacc[1] = MFMA16(pa[1][0], vone, Lacc[1]);                                  \
    Lacc[1] = MFMA16(pa[1][1], vone, Lacc[1]);                                  \
    bf16x8 Vf[4][2];                                                            \
    _Pragma("unroll") for (int dt = 0; dt < 4; dt++) {                          \
      Vf[dt][0] = *(const bf16x8*)&Vs[off0 + dt * 1024];                        \
      Vf[dt][1] = *(const bf16x8*)&Vs[off1 + dt * 1024];                        \
    }                                                                           \
    _Pragma("unroll") for (int qt2 = 0; qt2 < 2; qt2++)                         \
      _Pragma("unroll") for (int dt = 0; dt < 4; dt++) {                        \
        O[qt2][dt] = MFMA16(pa[qt2][0], Vf[dt][0], O[qt2][dt]);                 \
        O[qt2][dt] = MFMA16(pa[qt2][1], Vf[dt][1], O[qt2][dt]);                 \
      }                                                                         \
    __syncthreads();                                                            \
  }

  for (int kt2 = 0; kt2 < 15; kt2++) {
    ITER(0, 1)
    ITER(1, 1)
  }
  ITER(0, 1)
  ITER(1, 0)
#undef ITER
#undef STAGE

  // epilogue: Lacc[qt2][j] = row-sum for q = qt2*16 + quad*4 + j (all c equal)
  int b_ = bh >> 4, h = bh & 15;
#pragma unroll
  for (int qt2 = 0; qt2 < 2; qt2++) {
    f32x4 linv;
#pragma unroll
    for (int j = 0; j < 4; j++) linv[j] = 1.0f / Lacc[qt2][j];
#pragma unroll
    for (int j = 0; j < 4; j++) {
      int n = qt * 64 + w * 32 + qt2 * 16 + quad * 4 + j;
      u16* op = ot + (((size_t)b_ * 2048 + n) * 16 + h) * 64;
#pragma unroll
      for (int dt = 0; dt < 4; dt++)
        op[dt * 16 + c] = f2bf(O[qt2][dt][j] * linv[j]);
    }
  }
}

// ---------------- output projection GEMM (fp32 out), 64x64 tile, 4/CU ------
__global__ __launch_bounds__(256) void gemm_out(
    const u16* __restrict__ Aot, const u16* __restrict__ wob,
    const float* __restrict__ bo, float* __restrict__ out)
{
  __shared__ u16 As[64 * 64];
  __shared__ u16 Bs[64 * 64];
  int tid = threadIdx.x, w = tid >> 6, lane = tid & 63;
  int c = lane & 15, quad = lane >> 4;
  int bm = blockIdx.x, bn = blockIdx.y;
  int wm = w >> 1, wn = w & 1;
  f32x4 acc[2][2] = {};
  for (int k0 = 0; k0 < 1024; k0 += 64) {
#pragma unroll
    for (int i = 0; i < 2; i++) {
      int seg = i * 256 + tid;
      int row = seg >> 3, pseg = seg & 7;
      int lseg = pseg ^ (row & 7);
      gld16(Aot + (size_t)(bm * 64 + row) * 1024 + k0 + lseg * 8, &As[seg * 8]);
    }
#pragma unroll
    for (int i = 0; i < 2; i++) {
      int seg = i * 256 + tid;
      int row = seg >> 3, pseg = seg & 7;
      int lseg = pseg ^ (row & 7);
      gld16(wob + (size_t)(bn * 64 + row) * 1024 + k0 + lseg * 8, &Bs[seg * 8]);
    }
    __syncthreads();
#pragma unroll
    for (int ks = 0; ks < 2; ks++) {
      bf16x8 af[2], bfr[2];
#pragma unroll
      for (int mt = 0; mt < 2; mt++) {
        int row = wm * 32 + mt * 16 + c;
        int cseg = (ks * 4 + quad) ^ (row & 7);
        af[mt] = *(const bf16x8*)&As[(row * 8 + cseg) * 8];
      }
#pragma unroll
      for (int nt = 0; nt < 2; nt++) {
        int row = wn * 32 + nt * 16 + c;
        int cseg = (ks * 4 + quad) ^ (row & 7);
        bfr[nt] = *(const bf16x8*)&Bs[(row * 8 + cseg) * 8];
      }
#pragma unroll
      for (int mt = 0; mt < 2; mt++)
#pragma unroll
        for (int nt = 0; nt < 2; nt++)
          acc[mt][nt] = MFMA16(af[mt], bfr[nt], acc[mt][nt]);
    }
    __syncthreads();
  }
#pragma unroll
  for (int nt = 0; nt < 2; nt++) {
    int o = bn * 64 + wn * 32 + nt * 16 + c;
    float bval = bo[o];
#pragma unroll
    for (int mt = 0; mt < 2; mt++)
#pragma unroll
      for (int j = 0; j < 4; j++) {
        int m = bm * 64 + wm * 32 + mt * 16 + quad * 4 + j;
        out[(size_t)m * 1024 + o] = acc[mt][nt][j] + bval;
      }
  }
}

extern "C" void kernel_launch(void* const* d_in, const int* in_sizes, int n_in,
                              void* d_out, int out_size, void* d_ws, size_t ws_size,
                              hipStream_t stream)
{
  const float* x  = (const float*)d_in[0];
  const float* qu = (const float*)d_in[1];
  const float* wq = (const float*)d_in[2];
  const float* bq = (const float*)d_in[3];
  const float* wk = (const float*)d_in[4];
  const float* bk = (const float*)d_in[5];
  const float* wv = (const float*)d_in[6];
  const float* bv = (const float*)d_in[7];
  const float* wo = (const float*)d_in[8];
  const float* bo = (const float*)d_in[9];
  float* out = (float*)d_out;
  char* ws = (char*)d_ws;
  u16* xb  = (u16*)(ws + (size_t)0);          // 8 MB
  u16* qub = (u16*)(ws + ((size_t)8  << 20)); // 8 MB
  u16* wqb = (u16*)(ws + ((size_t)16 << 20)); // 2 MB
  u16* wkb = (u16*)(ws + ((size_t)18 << 20)); // 2 MB
  u16* wvb = (u16*)(ws + ((size_t)20 << 20)); // 2 MB
  u16* wob = (u16*)(ws + ((size_t)22 << 20)); // 2 MB
  u16* qhd = (u16*)(ws + ((size_t)24 << 20)); // 8 MB  Q-scaled [B,H,N,D]
  u16* khd = (u16*)(ws + ((size_t)32 << 20)); // 8 MB  K [B,H,N,D]
  u16* vtd = (u16*)(ws + ((size_t)40 << 20)); // 8 MB  V^T permuted [B,H,D,N']
  u16* otd = (u16*)(ws + ((size_t)48 << 20)); // 8 MB  attn out [B,N,H,D]

  cast_all<<<12288, 256, 0, stream>>>(x, qu, wq, wk, wv, wo,
                                      xb, qub, wqb, wkb, wvb, wob);
  gemm_qkv<<<dim3(64, 8, 3), 256, 0, stream>>>(qub, xb, wqb, wkb, wvb,
                                               bq, bk, bv, qhd, khd, vtd);
  attn<<<dim3(32, 32), 128, 0, stream>>>(qhd, khd, vtd, otd);
  gemm_out<<<dim3(64, 16), 256, 0, stream>>>(otd, wob, bo, out);
}